// Round 4
// baseline (251.451 us; speedup 1.0000x reference)
//
#include <hip/hip_runtime.h>
#include <hip/hip_fp16.h>

#define VOL    256
#define NPROJ  256
#define NDET   384
#define NS     256
#define PST    258                 // padded texture width (ux in [0,257])
#define GIMG   (PST * PST)         // entries per batch image
#define NBATCH 2
#define NCHUNK 4                   // s-split: one wave per chunk
#define NREG   6                   // y-regions staged through LDS
#define MAXROW 44                  // max staged rows per region
#define LDSW   (MAXROW * PST)      // 11352 dwords = 45408 B

// region r covers uy in [ULO[r], UHI[r]]; stages texture rows ULO..UHI+1
__device__ __constant__ int c_ulo[NREG] = {0, 43, 86, 129, 172, 215};
__device__ __constant__ int c_uhi[NREG] = {42, 85, 128, 171, 214, 256};

// Build horizontal-pair fp16 texture:
//   G[b][uy][ux] = half2{ P(uy,ux), P(uy,ux+1) }, P = zero-padded image.
__global__ void pair_build_kernel(const float* __restrict__ src, unsigned* __restrict__ G) {
    int idx = blockIdx.x * blockDim.x + threadIdx.x;   // over NBATCH*GIMG
    if (idx >= NBATCH * GIMG) return;
    int b   = idx / GIMG;
    int rem = idx - b * GIMG;
    int uy  = rem / PST;
    int ux  = rem - uy * PST;
    int r   = uy - 1;
    bool rin = (unsigned)r < (unsigned)VOL;
    int c0  = ux - 1;
    const float* im = src + (b << 16);
    float v0 = (rin && (unsigned)c0 < (unsigned)VOL) ? im[(r << 8) + c0] : 0.0f;
    float v1 = (rin && (unsigned)ux < (unsigned)VOL) ? im[(r << 8) + ux] : 0.0f;
    __half2 h = __floats2half2_rn(v0, v1);
    G[idx] = *reinterpret_cast<unsigned*>(&h);
}

// Block = 256 threads = 64 rays x 4 s-chunks. Loops 6 y-regions:
// stage region rows into LDS, process samples whose uy lands in region.
__global__ __launch_bounds__(256) void fanproj_kernel(const unsigned* __restrict__ G,
                                                      float* __restrict__ out) {
    __shared__ uint2 sG2[LDSW / 2];                    // 45408 B, 3 blocks/CU
    uint* sGu = reinterpret_cast<uint*>(sG2);

    int lane  = threadIdx.x & 63;
    int chunk = threadIdx.x >> 6;                      // 0..3
    int ray   = (blockIdx.x << 6) + lane;              // b*P*D + p*D + d
    int d     = ray % NDET;
    int pb    = ray / NDET;
    int p     = pb & (NPROJ - 1);
    int b     = pb >> 8;

    const float dt = 1.4142135623730951f;              // diag / NS = sqrt(2)
    const float t0 = 219.68777079743137f;              // SID - diag/2 + 0.5*dt

    float theta = (float)p * (6.283185307179586f / (float)NPROJ);
    float st, ct;
    sincosf(theta, &st, &ct);

    float srcx = -400.0f * ct;
    float srcy = -400.0f * st;
    float off  = ((float)d - 191.5f) * 1.2f;
    float rx   = fmaf(800.0f, ct, -off * st);
    float ry   = fmaf(800.0f, st,  off * ct);
    float n2   = rx * rx + ry * ry;
    float rn   = rsqrtf(n2);
    rn = rn * (1.5f - 0.5f * n2 * rn * rn);            // one Newton step
    rx *= rn;
    ry *= rn;

    float bx = fmaf(t0, rx, srcx) + 127.5f;            // +(VOL-1)/2 folded in
    float by = fmaf(t0, ry, srcy) + 127.5f;
    float sx = dt * rx;
    float sy = dt * ry;
    float inv_sy = 1.0f / sy;                          // inf ok (guarded below)

    int cLo = chunk << 6;                              // this wave's s-window
    int cHi = cLo + 63;

    const uint2* gbase = reinterpret_cast<const uint2*>(G) + (size_t)b * (GIMG / 2);

    float acc = 0.0f;
#pragma unroll
    for (int r = 0; r < NREG; ++r) {
        int ulo   = c_ulo[r];
        int uhi   = c_uhi[r];
        int nrows = uhi - ulo + 2;

        __syncthreads();                               // prior pass done reading LDS
        // stage texture rows [ulo, ulo+nrows) — contiguous dwords
        {
            const uint2* srcp = gbase + (ulo * PST) / 2;
            int cnt2 = nrows * (PST / 2);              // <= 5676
            for (int i = threadIdx.x; i < cnt2; i += 256)
                sG2[i] = srcp[i];
        }
        __syncthreads();

        // s-window where uy can be in [ulo, uhi]:  y in [ulo-1, uhi)
        float lo_y = (float)(ulo - 1);
        float hi_y = (float)uhi;
        float s0f, s1f;
        if (fabsf(sy) > 1e-6f) {
            float a  = (lo_y - by) * inv_sy;
            float bq = (hi_y - by) * inv_sy;
            s0f = fminf(a, bq) - 2.0f;
            s1f = fmaxf(a, bq) + 2.0f;
        } else {
            bool inr = (by >= lo_y - 2.0f) && (by <= hi_y + 2.0f);
            s0f = inr ? -1.0f : 1e9f;
            s1f = inr ? 1e9f : -1.0f;
        }
        int slo = max(cLo, (int)s0f);
        int shi = min(cHi, (int)s1f);

        unsigned uspan = (unsigned)(uhi - ulo);
        float sf = (float)slo;
        for (int s = slo; s <= shi; ++s) {
            float y = fmaf(sf, sy, by);
            float x = fmaf(sf, sx, bx);
            sf += 1.0f;
            float yf = floorf(y);
            float xf = floorf(x);
            int y0 = (int)yf;
            int x0 = (int)xf;
            unsigned uyl = (unsigned)(y0 + 1 - ulo);   // local staged row
            unsigned ux  = (unsigned)(x0 + 1);
            // exact membership: uy in region AND footprint x-valid
            if (uyl <= uspan && ux <= 256u) {
                float wx = x - xf;
                float wy = y - yf;
                const uint* rowp = sGu + uyl * PST + ux;
                uint qt = rowp[0];                     // {v(y0,x0),   v(y0,x0+1)}
                uint qb = rowp[PST];                   // {v(y0+1,x0), v(y0+1,x0+1)}
                __half2 ht = *reinterpret_cast<__half2*>(&qt);
                __half2 hb = *reinterpret_cast<__half2*>(&qb);
                float2 rt = __half22float2(ht);
                float2 rb = __half22float2(hb);
                float top = fmaf(wx, rt.y - rt.x, rt.x);
                float bot = fmaf(wx, rb.y - rb.x, rb.x);
                acc = fmaf(wy, bot - top, top) + acc;
            }
        }
    }

    // reduce the 4 chunk-partials through LDS (reuse staging buffer)
    __syncthreads();
    float* part = reinterpret_cast<float*>(sG2);
    if (chunk > 0) part[((chunk - 1) << 6) + lane] = acc;
    __syncthreads();
    if (chunk == 0) {
        acc += part[lane] + part[64 + lane] + part[128 + lane];
        out[ray] = acc * dt;
    }
}

extern "C" void kernel_launch(void* const* d_in, const int* in_sizes, int n_in,
                              void* d_out, int out_size, void* d_ws, size_t ws_size,
                              hipStream_t stream) {
    const float* x  = (const float*)d_in[0];
    float* out      = (float*)d_out;
    unsigned* G     = (unsigned*)d_ws;                 // NBATCH*GIMG*4B = 532 KB

    int nent = NBATCH * GIMG;                          // 133128
    pair_build_kernel<<<(nent + 255) / 256, 256, 0, stream>>>(x, G);

    int nrays = NBATCH * NPROJ * NDET;                 // 196608
    fanproj_kernel<<<nrays / 64, 256, 0, stream>>>(G, out);  // 768 blocks
}

// Round 5
// 105.219 us; speedup vs baseline: 2.3898x; 2.3898x over previous
//
#include <hip/hip_runtime.h>
#include <hip/hip_fp16.h>

#define VOL    256
#define NPROJ  256
#define NDET   384
#define NS     256
#define PROW   129                 // padded-row stride in DWORDS (258 halves)
#define PDW    (258 * PROW + 2)    // dwords per padded image + 2 spare = 33284
#define PV4    (PDW / 4)           // 8321 uint4
#define NBATCH 2
#define TPB    768                 // 12 waves; 1 block/CU; 256 blocks exact

// Zero-padded fp16 image in global ws, one dword = 2 adjacent halves.
// hpad[b] rows uy in [0,257], cols ux in [0,257]; value = img[uy-1][ux-1] or 0.
__global__ void pad_build_kernel(const float* __restrict__ src, uint* __restrict__ dst) {
    int idx = blockIdx.x * blockDim.x + threadIdx.x;   // over NBATCH*PDW
    if (idx >= NBATCH * PDW) return;
    int b = idx / PDW;
    int d = idx - b * PDW;
    uint val = 0u;
    if (d < 258 * PROW) {
        int uy = d / PROW;
        int q  = d - uy * PROW;
        int r  = uy - 1;
        int c0 = 2 * q - 1;                            // ux = 2q   -> col 2q-1
        int c1 = 2 * q;                                // ux = 2q+1 -> col 2q
        const float* im = src + (b << 16);
        float v0 = 0.0f, v1 = 0.0f;
        if ((unsigned)r < (unsigned)VOL) {
            if ((unsigned)c0 < (unsigned)VOL) v0 = im[(r << 8) + c0];
            if ((unsigned)c1 < (unsigned)VOL) v1 = im[(r << 8) + c1];
        }
        __half2 h = __floats2half2_rn(v0, v1);
        val = *reinterpret_cast<uint*>(&h);
    }
    dst[idx] = val;
}

// One block per CU: stage whole padded fp16 image into LDS (130 KB), then
// each thread integrates its own ray. 2x ds_read2_b32 per bilinear sample.
__global__ __launch_bounds__(TPB) void fanproj_kernel(const uint4* __restrict__ G,
                                                      float* __restrict__ out) {
    __shared__ uint4 s4[PV4];                          // 133,136 B
    const uint* sImg = reinterpret_cast<const uint*>(s4);

    int tid = threadIdx.x;
    int ray = blockIdx.x * TPB + tid;                  // b*P*D + p*D + d
    int b   = blockIdx.x >> 7;                         // 128 blocks per batch

    // stage this batch's image (contiguous uint4 copy)
    {
        const uint4* gb = G + (size_t)b * PV4;
        for (int i = tid; i < PV4; i += TPB) s4[i] = gb[i];
    }

    int d  = ray % NDET;
    int pb = ray / NDET;
    int p  = pb & (NPROJ - 1);

    const float dt = 1.4142135623730951f;              // diag / NS = sqrt(2)
    const float t0 = 219.68777079743137f;              // SID - diag/2 + 0.5*dt

    float theta = (float)p * (6.283185307179586f / (float)NPROJ);
    float st, ct;
    sincosf(theta, &st, &ct);

    float srcx = -400.0f * ct;
    float srcy = -400.0f * st;
    float off  = ((float)d - 191.5f) * 1.2f;
    float rx   = fmaf(800.0f, ct, -off * st);
    float ry   = fmaf(800.0f, st,  off * ct);
    float n2   = rx * rx + ry * ry;
    float rn   = rsqrtf(n2);
    rn = rn * (1.5f - 0.5f * n2 * rn * rn);            // one Newton step
    rx *= rn;
    ry *= rn;

    float bx = fmaf(t0, rx, srcx) + 127.5f;            // +(VOL-1)/2 folded in
    float by = fmaf(t0, ry, srcy) + 127.5f;
    float sx = dt * rx;
    float sy = dt * ry;

    __syncthreads();                                   // LDS image ready

    float acc = 0.0f;
    float sf  = 0.0f;
#pragma unroll 4
    for (int s = 0; s < NS; ++s) {
        float x = fmaf(sf, sx, bx);
        float y = fmaf(sf, sy, by);
        sf += 1.0f;
        float xf = floorf(x);
        float yf = floorf(y);
        int x0 = (int)xf;
        int y0 = (int)yf;
        unsigned ux = (unsigned)(x0 + 1);
        unsigned uy = (unsigned)(y0 + 1);
        // x0,y0 in [-1,255]: footprint inside padded image; else contributes 0.
        if (ux <= 256u && uy <= 256u) {
            float wx = x - xf;
            float wy = y - yf;
            int base = uy * PROW + (ux >> 1);
            uint d0 = sImg[base];                      // merged -> ds_read2_b32
            uint d1 = sImg[base + 1];
            uint d2 = sImg[base + PROW];               // merged -> ds_read2_b32
            uint d3 = sImg[base + PROW + 1];
            unsigned sh = (ux & 1u) << 4;              // half-select by x parity
            uint tw = __builtin_amdgcn_alignbit(d1, d0, sh);  // {v(y0,x0),v(y0,x0+1)}
            uint bw = __builtin_amdgcn_alignbit(d3, d2, sh);  // {v(y1,x0),v(y1,x0+1)}
            __half2 ht = *reinterpret_cast<__half2*>(&tw);
            __half2 hb = *reinterpret_cast<__half2*>(&bw);
            float2 rt = __half22float2(ht);
            float2 rb = __half22float2(hb);
            float top = fmaf(wx, rt.y - rt.x, rt.x);
            float bot = fmaf(wx, rb.y - rb.x, rb.x);
            acc = fmaf(wy, bot - top, top) + acc;
        }
    }
    out[ray] = acc * dt;
}

extern "C" void kernel_launch(void* const* d_in, const int* in_sizes, int n_in,
                              void* d_out, int out_size, void* d_ws, size_t ws_size,
                              hipStream_t stream) {
    const float* x  = (const float*)d_in[0];
    float* out      = (float*)d_out;
    uint* hpad      = (uint*)d_ws;                     // NBATCH*PDW*4 = 266 KB

    int ndw = NBATCH * PDW;                            // 66568
    pad_build_kernel<<<(ndw + 255) / 256, 256, 0, stream>>>(x, hpad);

    // 256 blocks x 768 threads = 196608 rays exactly; blocks are batch-pure
    fanproj_kernel<<<256, TPB, 0, stream>>>((const uint4*)hpad, out);
}